// Round 12
// baseline (2104.143 us; speedup 1.0000x reference)
//
#include <hip/hip_runtime.h>

// KalmanNet recurrent step, MFMA fp16, r12: 512 threads, 256 VGPRs/wave.
//
// r5-r11 synthesis: 1024-thr blocks force 4 waves/SIMD => 128-reg cap =>
// 64 arch VGPRs => unavoidable spills (WRITE 170-330 MB across rounds) =>
// scratch stream evicts the 1.2 MB weight set from per-XCD L2 => the
// 1.4-1.6 TB/s L2-fill path becomes the wall. r11 (BR=64) proved traffic
// reduction helps per-CU but idled half the chip (128 blocks).
//
// r12: BR=32 (grid 256 = full chip), NTHR=512 (8 waves, 1 block/CU via
// 94KB LDS), waves_per_eu(2,2) => 256 unified regs/wave. Per-wave work
// doubles vs r8; phase-C arch live ~70 + 64 acc fits the budget with
// room, so the allocator need not spill and the scheduler can hoist
// loads. All asm/sched_barrier removed; t-loop pinned no-unroll.
// Numerics = r8 exactly (hi/lo A everywhere): absmax 4.88e-4.
//
// Work split (8 waves): gates 13 j-tile quads: waves 0-4 own {w, w+8},
// 5-7 own {w}; W1 30 tiles: {w, w+8, w+16} + {w+24 if w<6}; W2 20 tiles:
// {w, w+8} + {w+16 if w<4}; W3: waves 0-3 = (k-half, m-half). GRU in
// registers; h in A-fragment slots k=480+j; state in parity LDS.
// Bias folding: W1 ones-row k=8 -> b1; h-pad k=680==1.0 + g_w2 row 200 -> b2.
//
// Fragment maps (verified r2-r11): A/B k = kt*32 + (lane>>4)*8 + i,
// A row / B col = lane&15; C/D col = lane&15, row = (lane>>4)*4 + reg.

namespace {

constexpr int T_STEPS = 32;
constexpr int BATCH   = 8192;
constexpr int H1      = 480;
constexpr int HID     = 200;
constexpr int H2      = 320;
constexpr int BR      = 32;    // batch rows per block (2 MFMA m-tiles)
constexpr int NTHR    = 512;   // 8 waves, 2/SIMD, 1 block/CU, 256 regs/wave
constexpr int KTG     = 22;    // gates K tiles (704 = 480 a1 + 224 h/pad)
constexpr int NTG     = 52;    // 4 groups x 13 real j-tiles
constexpr int NTW1    = 30;    // W1 real col tiles (480/16)
constexpr int NT2     = 20;    // W2 real col tiles (320/16)
constexpr int KT2     = 7;     // W2 K tiles (224)
constexpr int KT3     = 10;    // W3 K tiles (320)

using f16x8 = __attribute__((ext_vector_type(8))) _Float16;
using f32x4 = __attribute__((ext_vector_type(4))) float;

__device__ _Float16 g_w1[NTW1 * 512];          // [nt][lane][8], k=8 row = b1
__device__ _Float16 g_wcat[NTG * KTG * 512];   // [grp*13+tile][kt][lane][8]
__device__ _Float16 g_w2[NT2 * KT2 * 512];     // [nt][kt][lane][8], k_h=200 = b2
__device__ _Float16 g_w3[KT3 * 512];           // [kt][lane][8], cols 8..15 = 0

#define MFMA16(A, B, C) __builtin_amdgcn_mfma_f32_16x16x32_f16((A), (B), (C), 0, 0, 0)

__device__ __forceinline__ float sigmoid_(float x) { return 1.f / (1.f + __expf(-x)); }
__device__ __forceinline__ float tanh_(float x) {
  x = fminf(fmaxf(x, -15.f), 15.f);
  const float e = __expf(-2.f * x);
  return (1.f - e) / (1.f + e);
}
__device__ __forceinline__ f16x8 f16x8_zero() {
  f16x8 v;
#pragma unroll
  for (int i = 0; i < 8; ++i) v[i] = (_Float16)0.f;
  return v;
}

// element (k, r) -> flat half index in A-fragment LDS layout
// [kt][m=r>>4][lane=((k&31)>>3)*16 + (r&15)][i=k&7]
__device__ __forceinline__ int afrag_off(int k, int r) {
  const int kt = k >> 5, kk = k & 31;
  return ((kt * 2 + (r >> 4)) * 512) + ((((kk >> 3) << 4) | (r & 15)) * 8) + (kk & 7);
}

// ---------------- weight pre-pack ----------------
__global__ __launch_bounds__(256) void prep_kernel(
    const float* __restrict__ W1, const float* __restrict__ b1,
    const float* __restrict__ Wg, const float* __restrict__ Ug,
    const float* __restrict__ W2, const float* __restrict__ b2,
    const float* __restrict__ W3) {
  const int idx = blockIdx.x * 256 + threadIdx.x;
  constexpr int TOTW1 = NTW1 * 512;
  constexpr int TOT1  = NTG * KTG * 512;
  constexpr int TOT2  = NT2 * KT2 * 512;
  constexpr int TOT3  = KT3 * 512;
  if (idx < TOTW1) {
    const int i = idx & 7, l = (idx >> 3) & 63, nt = idx >> 9;
    const int g = l >> 4, c = l & 15;
    const int k = g * 8 + i, col = nt * 16 + c;   // col < 480 always
    float wv = 0.f;
    if (k < 8) wv = W1[k * H1 + col];
    else if (k == 8) wv = b1[col];
    g_w1[idx] = (_Float16)wv;
  } else if (idx < TOTW1 + TOT1) {
    const int id = idx - TOTW1;
    const int i = id & 7, l = (id >> 3) & 63, nk = id >> 9;
    const int kt = nk % KTG, nt = nk / KTG;
    const int g = l >> 4, c = l & 15;
    const int k = kt * 32 + g * 8 + i;        // 0..703
    const int grp = nt / 13;                  // 0=z 1=r 2=xh 3=hh
    const int jj = (nt - grp * 13) * 16 + c;  // 0..207
    float wv = 0.f;
    if (jj < HID) {
      if (grp == 0) {
        if (k < H1) wv = Wg[k * 600 + jj];
        else if (k < H1 + HID) wv = Ug[(k - H1) * 600 + jj];
      } else if (grp == 1) {
        if (k < H1) wv = Wg[k * 600 + 200 + jj];
        else if (k < H1 + HID) wv = Ug[(k - H1) * 600 + 200 + jj];
      } else if (grp == 2) {
        if (k < H1) wv = Wg[k * 600 + 400 + jj];           // xh: a1 rows only
      } else {
        if (k >= H1 && k < H1 + HID) wv = Ug[(k - H1) * 600 + 400 + jj];  // hh
      }
    }
    g_wcat[id] = (_Float16)wv;
  } else if (idx < TOTW1 + TOT1 + TOT2) {
    const int id = idx - TOTW1 - TOT1;
    const int i = id & 7, l = (id >> 3) & 63, nk = id >> 9;
    const int kt = nk % KT2, nt = nk / KT2;
    const int g = l >> 4, c = l & 15;
    const int k = kt * 32 + g * 8 + i;        // 0..223
    const int col = nt * 16 + c;              // 0..319 (all real)
    float wv = 0.f;
    if (k < HID) wv = W2[k * H2 + col];
    else if (k == 200) wv = b2[col];          // ones-row at k_h=200 (k=680)
    g_w2[id] = (_Float16)wv;
  } else if (idx < TOTW1 + TOT1 + TOT2 + TOT3) {
    const int id = idx - TOTW1 - TOT1 - TOT2;
    const int i = id & 7, l = (id >> 3) & 63, kt = id >> 9;
    const int g = l >> 4, c = l & 15;
    const int k = kt * 32 + g * 8 + i;        // 0..319
    g_w3[id] = (_Float16)((c < 8) ? W3[k * 8 + c] : 0.f);
  }
}

// ---------------- main recurrent kernel ----------------
__global__
__attribute__((amdgpu_flat_work_group_size(NTHR, NTHR)))
__attribute__((amdgpu_waves_per_eu(2, 2)))
void knet_kernel(
    const float* __restrict__ y,    // [T,B,2]
    const float* __restrict__ Fm,   // [4,4]
    const float* __restrict__ Hm,   // [2,4]
    const float* __restrict__ bg,   // [2,600]
    const float* __restrict__ b3,   // [8]
    const float* __restrict__ hn0,  // [B,200]
    float* __restrict__ out)        // [T,B,4]
{
  // A-fragments of x_cat = [a1(480) | h(200) | 1.0 @680 | 0-pad]; a2 reuses
  // slots 0..9 between phase E and phase F.
  __shared__ alignas(16) _Float16 sAhi[KTG * 2 * 512];   // 45056 B
  __shared__ alignas(16) _Float16 sAlo[KTG * 2 * 512];   // 45056 B
  __shared__ alignas(16) float s_in8T[8][BR];
  __shared__ alignas(16) float s_kgp[2][BR][8];          // KG k-half partials
  __shared__ alignas(16) float s_bias[4][HID];
  __shared__ alignas(16) float s_fh[32];                 // Fm[16], Hm[8]
  __shared__ alignas(16) float s_b3[8];
  // persistent per-row filter state, double-buffered by t-parity (r8)
  __shared__ alignas(16) float s_prior2[2][BR][4];
  __shared__ alignas(16) float s_d2[2][BR][2];

  const int tid  = threadIdx.x;
  const int lane = tid & 63;
  const int wid  = __builtin_amdgcn_readfirstlane(tid >> 6);  // 0..7
  const int row0 = blockIdx.x * BR;
  const int rl   = lane & 31;
  const int g4   = (lane >> 4) << 2;
  const int ab   = lane * 8;
  const int c16  = lane & 15;

  // ---- init ----
  if (tid < HID) {
    s_bias[0][tid] = bg[tid]       + bg[600 + tid];   // z
    s_bias[1][tid] = bg[200 + tid] + bg[800 + tid];   // r
    s_bias[2][tid] = bg[400 + tid];                   // xh (input bias)
    s_bias[3][tid] = bg[1000 + tid];                  // hh (recurrent bias)
  }
  if (tid < 16) s_fh[tid] = Fm[tid];
  else if (tid < 24) s_fh[tid] = Hm[tid - 16];
  if (tid < 8) s_b3[tid] = b3[tid];
  if (tid < BR * 4) s_prior2[0][tid >> 2][tid & 3] = 0.f;
  if (tid < BR * 2) s_d2[0][tid >> 1][tid & 1] = 0.f;
  for (int e = tid; e < HID * BR; e += NTHR) {
    const int j = e >> 5, r = e & 31;
    const float h0 = hn0[(size_t)(row0 + r) * HID + j];
    const int off = afrag_off(480 + j, r);
    const _Float16 hi = (_Float16)h0;
    sAhi[off] = hi;
    sAlo[off] = (_Float16)(h0 - (float)hi);
  }
  for (int e = tid; e < 24 * BR; e += NTHR) {   // k 680..703: 1.0 then zeros
    const int k = 680 + (e >> 5), r = e & 31;
    const int off = afrag_off(k, r);
    sAhi[off] = (_Float16)((k == 680) ? 1.f : 0.f);
    sAlo[off] = (_Float16)0.f;
  }
  __syncthreads();

#pragma unroll 1
  for (int t = 0; t < T_STEPS; ++t) {
    const int p = t & 1;
    // ================= phase 1: F2(t-1) + A(t) + W1-GEMM(t) =================
    {
      float post[4] = {0.f, 0.f, 0.f, 0.f};
      if (t > 0) {
        float kg[8];
#pragma unroll
        for (int cc = 0; cc < 8; ++cc)
          kg[cc] = s_kgp[0][rl][cc] + s_kgp[1][rl][cc] + s_b3[cc];
        const float pd0 = s_d2[p][rl][0], pd1 = s_d2[p][rl][1];
#pragma unroll
        for (int m = 0; m < 4; ++m)
          post[m] = s_prior2[p][rl][m] + kg[2 * m] * pd0 + kg[2 * m + 1] * pd1;
        if (wid == 0 && lane < BR) {
          float4 o; o.x = post[0]; o.y = post[1]; o.z = post[2]; o.w = post[3];
          *(float4*)&out[((size_t)(t - 1) * BATCH + row0 + rl) * 4] = o;
        }
      }
      // ---- A: prior / innovation / features (redundant per wave) ----
      float opri[4], np[4];
#pragma unroll
      for (int m = 0; m < 4; ++m) opri[m] = s_prior2[p][rl][m];
#pragma unroll
      for (int m = 0; m < 4; ++m) {
        float s = 0.f;
#pragma unroll
        for (int j = 0; j < 4; ++j) s += s_fh[m * 4 + j] * post[j];
        np[m] = s;
      }
      float m0 = 0.f, m1 = 0.f;
#pragma unroll
      for (int m = 0; m < 4; ++m) { m0 += s_fh[16 + m] * np[m]; m1 += s_fh[20 + m] * np[m]; }
      const float2 yv = *(const float2*)&y[((size_t)t * BATCH + row0 + rl) * 2];
      const float d0 = yv.x - m0;
      const float d1 = yv.y - m1;
      float dx[4], ssx = 0.f;
#pragma unroll
      for (int m = 0; m < 4; ++m) { dx[m] = post[m] - opri[m]; ssx += dx[m] * dx[m]; }
      const float idx_ = rsqrtf(fmaxf(ssx, 1e-12f));
      const float idy_ = rsqrtf(fmaxf(d0 * d0 + d1 * d1, 1e-12f));
      if (lane < BR) {   // identical values from all waves: benign
#pragma unroll
        for (int m = 0; m < 4; ++m) s_prior2[p ^ 1][rl][m] = np[m];
        s_d2[p ^ 1][rl][0] = d0;
        s_d2[p ^ 1][rl][1] = d1;
        const float n0 = d0 * idy_, n1 = d1 * idy_;
        s_in8T[0][rl] = n0; s_in8T[1][rl] = n1;
        s_in8T[2][rl] = n0; s_in8T[3][rl] = n1;
#pragma unroll
        for (int m = 0; m < 4; ++m) s_in8T[4 + m][rl] = dx[m] * idx_;
      }
    }
    {   // ---- W1-GEMM: tiles {w, w+8, w+16} + {w+24 if w<6} ----
      f16x8 ah0 = f16x8_zero(), al0 = f16x8_zero();
      f16x8 ah1 = f16x8_zero(), al1 = f16x8_zero();
      const int g = lane >> 4;
      if (g == 0) {
#pragma unroll
        for (int i = 0; i < 8; ++i) {
          const float v0 = s_in8T[i][c16];
          const float v1 = s_in8T[i][c16 + 16];
          const _Float16 h0 = (_Float16)v0; ah0[i] = h0; al0[i] = (_Float16)(v0 - (float)h0);
          const _Float16 h1 = (_Float16)v1; ah1[i] = h1; al1[i] = (_Float16)(v1 - (float)h1);
        }
      } else if (g == 1) {
        ah0[0] = (_Float16)1.f;   // ones-row k=8 -> b1
        ah1[0] = (_Float16)1.f;
      }
      const bool has4 = (wid < 6);
      f32x4 p00 = {0.f,0.f,0.f,0.f}, p01 = p00, p10 = p00, p11 = p00;
      f32x4 p20 = p00, p21 = p00, p30 = p00, p31 = p00;
      const f16x8 wa = *(const f16x8*)&g_w1[(size_t)wid * 512 + ab];
      const f16x8 wb = *(const f16x8*)&g_w1[(size_t)(wid + 8) * 512 + ab];
      const f16x8 wc = *(const f16x8*)&g_w1[(size_t)(wid + 16) * 512 + ab];
      p00 = MFMA16(ah0, wa, p00); p00 = MFMA16(al0, wa, p00);
      p01 = MFMA16(ah1, wa, p01); p01 = MFMA16(al1, wa, p01);
      p10 = MFMA16(ah0, wb, p10); p10 = MFMA16(al0, wb, p10);
      p11 = MFMA16(ah1, wb, p11); p11 = MFMA16(al1, wb, p11);
      p20 = MFMA16(ah0, wc, p20); p20 = MFMA16(al0, wc, p20);
      p21 = MFMA16(ah1, wc, p21); p21 = MFMA16(al1, wc, p21);
      if (has4) {
        const f16x8 wd = *(const f16x8*)&g_w1[(size_t)(wid + 24) * 512 + ab];
        p30 = MFMA16(ah0, wd, p30); p30 = MFMA16(al0, wd, p30);
        p31 = MFMA16(ah1, wd, p31); p31 = MFMA16(al1, wd, p31);
      }
#define ASTORE(A0, A1, COLBASE)                                      \
      { const int col = (COLBASE) + c16;                             \
        _Pragma("unroll")                                            \
        for (int reg = 0; reg < 4; ++reg) {                          \
          const float v0 = fmaxf(A0[reg], 0.f);                      \
          const float v1 = fmaxf(A1[reg], 0.f);                      \
          const int o0 = afrag_off(col, g4 + reg);                   \
          const int o1 = afrag_off(col, 16 + g4 + reg);              \
          const _Float16 q0 = (_Float16)v0, q1 = (_Float16)v1;       \
          sAhi[o0] = q0; sAlo[o0] = (_Float16)(v0 - (float)q0);      \
          sAhi[o1] = q1; sAlo[o1] = (_Float16)(v1 - (float)q1);      \
        } }
      ASTORE(p00, p01, wid * 16)
      ASTORE(p10, p11, (wid + 8) * 16)
      ASTORE(p20, p21, (wid + 16) * 16)
      if (has4) ASTORE(p30, p31, (wid + 24) * 16)
    }
    __syncthreads();

    // ==== phase C: gates GEMM; waves 0-4 own j-quads {w, w+8}, 5-7 {w} ====
    f32x4 aZ0 = {0.f,0.f,0.f,0.f}, aZ1 = aZ0, aR0 = aZ0, aR1 = aZ0;
    f32x4 aX0 = aZ0, aX1 = aZ0, aH0 = aZ0, aH1 = aZ0;
    f32x4 bZ0 = aZ0, bZ1 = aZ0, bR0 = aZ0, bR1 = aZ0;
    f32x4 bX0 = aZ0, bX1 = aZ0, bH0 = aZ0, bH1 = aZ0;
    const bool two = (wid < 5);
    {
      const _Float16* az_ = g_wcat + ((size_t)(0  + wid) * KTG) * 512 + ab;
      const _Float16* ar2 = g_wcat + ((size_t)(13 + wid) * KTG) * 512 + ab;
      const _Float16* ax_ = g_wcat + ((size_t)(26 + wid) * KTG) * 512 + ab;
      const _Float16* ah2 = g_wcat + ((size_t)(39 + wid) * KTG) * 512 + ab;
      const _Float16* bz_ = g_wcat + ((size_t)(8  + wid) * KTG) * 512 + ab;
      const _Float16* br2 = g_wcat + ((size_t)(21 + wid) * KTG) * 512 + ab;
      const _Float16* bx_ = g_wcat + ((size_t)(34 + wid) * KTG) * 512 + ab;
      const _Float16* bh2 = g_wcat + ((size_t)(47 + wid) * KTG) * 512 + ab;
#pragma unroll
      for (int kt = 0; kt < KTG; ++kt) {
        const int _o = kt * 1024 + ab;
        const f16x8 cah0 = *(const f16x8*)&sAhi[_o];
        const f16x8 cal0 = *(const f16x8*)&sAlo[_o];
        const f16x8 cah1 = *(const f16x8*)&sAhi[_o + 512];
        const f16x8 cal1 = *(const f16x8*)&sAlo[_o + 512];
        const f16x8 vz = *(const f16x8*)(az_ + kt * 512);
        const f16x8 vr = *(const f16x8*)(ar2 + kt * 512);
        const f16x8 vx = (kt < 15) ? *(const f16x8*)(ax_ + kt * 512)
                                   : *(const f16x8*)(ah2 + kt * 512);
        aZ0 = MFMA16(cah0, vz, aZ0);  aZ0 = MFMA16(cal0, vz, aZ0);
        aZ1 = MFMA16(cah1, vz, aZ1);  aZ1 = MFMA16(cal1, vz, aZ1);
        aR0 = MFMA16(cah0, vr, aR0);  aR0 = MFMA16(cal0, vr, aR0);
        aR1 = MFMA16(cah1, vr, aR1);  aR1 = MFMA16(cal1, vr, aR1);
        if (kt < 15) {
          aX0 = MFMA16(cah0, vx, aX0); aX0 = MFMA16(cal0, vx, aX0);
          aX1 = MFMA16(cah1, vx, aX1); aX1 = MFMA16(cal1, vx, aX1);
        } else {
          aH0 = MFMA16(cah0, vx, aH0); aH0 = MFMA16(cal0, vx, aH0);
          aH1 = MFMA16(cah1, vx, aH1); aH1 = MFMA16(cal1, vx, aH1);
        }
        if (two) {
          const f16x8 wz = *(const f16x8*)(bz_ + kt * 512);
          const f16x8 wr = *(const f16x8*)(br2 + kt * 512);
          const f16x8 wx = (kt < 15) ? *(const f16x8*)(bx_ + kt * 512)
                                     : *(const f16x8*)(bh2 + kt * 512);
          bZ0 = MFMA16(cah0, wz, bZ0);  bZ0 = MFMA16(cal0, wz, bZ0);
          bZ1 = MFMA16(cah1, wz, bZ1);  bZ1 = MFMA16(cal1, wz, bZ1);
          bR0 = MFMA16(cah0, wr, bR0);  bR0 = MFMA16(cal0, wr, bR0);
          bR1 = MFMA16(cah1, wr, bR1);  bR1 = MFMA16(cal1, wr, bR1);
          if (kt < 15) {
            bX0 = MFMA16(cah0, wx, bX0); bX0 = MFMA16(cal0, wx, bX0);
            bX1 = MFMA16(cah1, wx, bX1); bX1 = MFMA16(cal1, wx, bX1);
          } else {
            bH0 = MFMA16(cah0, wx, bH0); bH0 = MFMA16(cal0, wx, bH0);
            bH1 = MFMA16(cah1, wx, bH1); bH1 = MFMA16(cal1, wx, bH1);
          }
        }
      }
    }
    __syncthreads();   // all h reads done before in-place h update

    // ================= phase D: in-register GRU update =================
    {
#define GRU1(AZ, AR, AX, AH, J, MB)                                      \
      { const float bz  = s_bias[0][J], brb = s_bias[1][J];              \
        const float bxh = s_bias[2][J], bhh = s_bias[3][J];              \
        _Pragma("unroll")                                                \
        for (int reg = 0; reg < 4; ++reg) {                              \
          const int r = (MB) * 16 + g4 + reg;                            \
          const int off = afrag_off(480 + (J), r);                       \
          const float hold = (float)sAhi[off] + (float)sAlo[off];        \
          const float z  = sigmoid_(AZ[reg] + bz);                       \
          const float rr = sigmoid_(AR[reg] + brb);                      \
          const float hc = tanh_((AX[reg] + bxh) + rr * (AH[reg] + bhh));\
          const float hn = z * hold + (1.f - z) * hc;                    \
          const _Float16 qh = (_Float16)hn;                              \
          sAhi[off] = qh;                                                \
          sAlo[off] = (_Float16)(hn - (float)qh);                       \
        } }
      const int j0 = wid * 16 + c16;            // <= 127 < 200: no guard
      GRU1(aZ0, aR0, aX0, aH0, j0, 0)
      GRU1(aZ1, aR1, aX1, aH1, j0, 1)
      if (two) {
        const int j1 = (wid + 8) * 16 + c16;    // 128..207: guard tail
        if (j1 < HID) {
          GRU1(bZ0, bR0, bX0, bH0, j1, 0)
          GRU1(bZ1, bR1, bX1, bH1, j1, 1)
        }
      }
#undef GRU1
    }
    __syncthreads();

    // ====== phase E: a2 = relu(h @ W2 + b2); tiles {w, w+8} + {w+16 w<4} ======
    {
      f32x4 e00 = {0.f,0.f,0.f,0.f}, e01 = e00, e10 = e00, e11 = e00;
      f32x4 e20 = e00, e21 = e00;
      const bool three = (wid < 4);
      const _Float16* w2a = g_w2 + ((size_t)wid * KT2) * 512 + ab;
      const _Float16* w2b = g_w2 + ((size_t)(wid + 8) * KT2) * 512 + ab;
      const _Float16* w2c = g_w2 + ((size_t)(wid + 16) * KT2) * 512 + ab;
#pragma unroll
      for (int qt = 0; qt < KT2; ++qt) {
        const int _o = (15 + qt) * 1024 + ab;
        const f16x8 cah0 = *(const f16x8*)&sAhi[_o];
        const f16x8 cal0 = *(const f16x8*)&sAlo[_o];
        const f16x8 cah1 = *(const f16x8*)&sAhi[_o + 512];
        const f16x8 cal1 = *(const f16x8*)&sAlo[_o + 512];
        const f16x8 ba = *(const f16x8*)(w2a + qt * 512);
        const f16x8 bb = *(const f16x8*)(w2b + qt * 512);
        e00 = MFMA16(cah0, ba, e00); e00 = MFMA16(cal0, ba, e00);
        e01 = MFMA16(cah1, ba, e01); e01 = MFMA16(cal1, ba, e01);
        e10 = MFMA16(cah0, bb, e10); e10 = MFMA16(cal0, bb, e10);
        e11 = MFMA16(cah1, bb, e11); e11 = MFMA16(cal1, bb, e11);
        if (three) {
          const f16x8 bc = *(const f16x8*)(w2c + qt * 512);
          e20 = MFMA16(cah0, bc, e20); e20 = MFMA16(cal0, bc, e20);
          e21 = MFMA16(cah1, bc, e21); e21 = MFMA16(cal1, bc, e21);
        }
      }
      ASTORE(e00, e01, wid * 16)
      ASTORE(e10, e11, (wid + 8) * 16)
      if (three) ASTORE(e20, e21, (wid + 16) * 16)
#undef ASTORE
    }
    __syncthreads();

    // ========== phase F: KG partials (waves 0..3 = m-half x k-half) ==========
    if (wid < 4) {
      const int mB = wid & 1, half = wid >> 1;
      f32x4 ka = {0.f, 0.f, 0.f, 0.f};
      const _Float16* w3p = g_w3 + ab;
#pragma unroll
      for (int q = 0; q < 5; ++q) {
        const int kt3 = half * 5 + q;
        const int _o = (kt3 * 2 + mB) * 512 + ab;
        const f16x8 ah = *(const f16x8*)&sAhi[_o];
        const f16x8 al = *(const f16x8*)&sAlo[_o];
        const f16x8 bw = *(const f16x8*)(w3p + kt3 * 512);
        ka = MFMA16(ah, bw, ka); ka = MFMA16(al, bw, ka);
      }
      if (c16 < 8) {
        const int rb = mB * 16 + g4;
#pragma unroll
        for (int reg = 0; reg < 4; ++reg) s_kgp[half][rb + reg][c16] = ka[reg];
      }
    }
    __syncthreads();
  }

  // ---- final F2 (t = T_STEPS, parity 0) ----
  {
    float kg[8];
#pragma unroll
    for (int cc = 0; cc < 8; ++cc)
      kg[cc] = s_kgp[0][rl][cc] + s_kgp[1][rl][cc] + s_b3[cc];
    const float pd0 = s_d2[0][rl][0], pd1 = s_d2[0][rl][1];
    if (wid == 0 && lane < BR) {
      float4 o;
      o.x = s_prior2[0][rl][0] + kg[0] * pd0 + kg[1] * pd1;
      o.y = s_prior2[0][rl][1] + kg[2] * pd0 + kg[3] * pd1;
      o.z = s_prior2[0][rl][2] + kg[4] * pd0 + kg[5] * pd1;
      o.w = s_prior2[0][rl][3] + kg[6] * pd0 + kg[7] * pd1;
      *(float4*)&out[((size_t)(T_STEPS - 1) * BATCH + row0 + rl) * 4] = o;
    }
  }
}

}  // namespace

extern "C" void kernel_launch(void* const* d_in, const int* in_sizes, int n_in,
                              void* d_out, int out_size, void* d_ws, size_t ws_size,
                              hipStream_t stream) {
  const float* y   = (const float*)d_in[0];
  const float* Fm  = (const float*)d_in[1];
  const float* Hm  = (const float*)d_in[2];
  const float* W1  = (const float*)d_in[3];
  const float* b1  = (const float*)d_in[4];
  const float* Wg  = (const float*)d_in[5];
  const float* Ug  = (const float*)d_in[6];
  const float* bg  = (const float*)d_in[7];
  const float* W2  = (const float*)d_in[8];
  const float* b2  = (const float*)d_in[9];
  const float* W3  = (const float*)d_in[10];
  const float* b3  = (const float*)d_in[11];
  const float* hn0 = (const float*)d_in[12];
  float* out = (float*)d_out;

  constexpr int PREP_TOT = (NTW1 + NTG * KTG + NT2 * KT2 + KT3) * 512;
  prep_kernel<<<(PREP_TOT + 255) / 256, 256, 0, stream>>>(W1, b1, Wg, Ug, W2, b2, W3);
  knet_kernel<<<BATCH / BR, NTHR, 0, stream>>>(y, Fm, Hm, bg, b3, hn0, out);
}

// Round 13
// 1210.383 us; speedup vs baseline: 1.7384x; 1.7384x over previous
//
#include <hip/hip_runtime.h>

// KalmanNet recurrent step, MFMA fp16, r13: r8 config + r11 precision trim.
//
// Matrix r8-r12: r8 (1024thr, BR32, 16 waves/CU, full chip) = 1349us best.
// r12 proved spills die with regs (VGPR 128, FETCH -28%) but 2 waves/SIMD
// kills TLP (2047us). r10/r11: traffic scales with block count; BR=32 at
// grid 256 is the full-chip optimum. r11 proved a1/a2 single-fp16 leaves
// absmax EXACTLY unchanged (4.88e-4) -- only h (recurrent) needs hi/lo.
//
// r13 = r8 with single-fp16 a1/a2: phase-C A-live halves (kt<15 region:
// 16 regs vs 32 => ~55-reg live set inside the 64-arch budget => spills
// mostly die), MFMA 264->174/wave, LDS reads -40%, LDS 90->64KB.
// All else byte-for-byte r8 (depth-1 pinned B prefetch, parity-LDS state,
// bias folding, work splits).
//
// Fragment maps (verified r2-r12): A/B k = kt*32 + (lane>>4)*8 + i,
// A row / B col = lane&15; C/D col = lane&15, row = (lane>>4)*4 + reg.

namespace {

constexpr int T_STEPS = 32;
constexpr int BATCH   = 8192;
constexpr int H1      = 480;
constexpr int HID     = 200;
constexpr int H2      = 320;
constexpr int BR      = 32;    // batch rows per block (2 MFMA m-tiles)
constexpr int NTHR    = 1024;  // 16 waves, 4/SIMD, 1 block/CU
constexpr int KTG     = 22;    // gates K tiles (704 = 480 a1 + 224 h/pad)
constexpr int KTA     = 15;    // a1 K tiles (480)
constexpr int NTG     = 52;    // 4 groups x 13 real j-tiles
constexpr int NTW1    = 30;    // W1 real col tiles (480/16)
constexpr int NT2     = 20;    // W2 real col tiles (320/16)
constexpr int KT2     = 7;     // W2 / h K tiles (224)
constexpr int KT3     = 10;    // W3 K tiles (320)

using f16x8 = __attribute__((ext_vector_type(8))) _Float16;
using f32x4 = __attribute__((ext_vector_type(4))) float;

__device__ _Float16 g_w1[NTW1 * 512];          // [nt][lane][8], k=8 row = b1
__device__ _Float16 g_wcat[NTG * KTG * 512];   // [grp*13+tile][kt][lane][8]
__device__ _Float16 g_w2[NT2 * KT2 * 512];     // [nt][kt][lane][8], k_h=200 = b2
__device__ _Float16 g_w3[KT3 * 512];           // [kt][lane][8], cols 8..15 = 0

#define MFMA16(A, B, C) __builtin_amdgcn_mfma_f32_16x16x32_f16((A), (B), (C), 0, 0, 0)
#define SBAR() __builtin_amdgcn_sched_barrier(0)

__device__ __forceinline__ float sigmoid_(float x) { return 1.f / (1.f + __expf(-x)); }
__device__ __forceinline__ float tanh_(float x) {
  x = fminf(fmaxf(x, -15.f), 15.f);
  const float e = __expf(-2.f * x);
  return (1.f - e) / (1.f + e);
}
__device__ __forceinline__ f16x8 f16x8_zero() {
  f16x8 v;
#pragma unroll
  for (int i = 0; i < 8; ++i) v[i] = (_Float16)0.f;
  return v;
}

// (k, r) -> flat half index; layout [kt][m=r>>4][lane=((k&31)>>3)*16+(r&15)][i=k&7]
__device__ __forceinline__ int fragoff(int k, int r) {
  const int kt = k >> 5, kk = k & 31;
  return kt * 1024 + ((r >> 4) * 512) + ((((kk >> 3) << 4) | (r & 15)) * 8) + (kk & 7);
}

// ---------------- weight pre-pack (identical to r8/r12) ----------------
__global__ __launch_bounds__(256) void prep_kernel(
    const float* __restrict__ W1, const float* __restrict__ b1,
    const float* __restrict__ Wg, const float* __restrict__ Ug,
    const float* __restrict__ W2, const float* __restrict__ b2,
    const float* __restrict__ W3) {
  const int idx = blockIdx.x * 256 + threadIdx.x;
  constexpr int TOTW1 = NTW1 * 512;
  constexpr int TOT1  = NTG * KTG * 512;
  constexpr int TOT2  = NT2 * KT2 * 512;
  constexpr int TOT3  = KT3 * 512;
  if (idx < TOTW1) {
    const int i = idx & 7, l = (idx >> 3) & 63, nt = idx >> 9;
    const int g = l >> 4, c = l & 15;
    const int k = g * 8 + i, col = nt * 16 + c;   // col < 480 always
    float wv = 0.f;
    if (k < 8) wv = W1[k * H1 + col];
    else if (k == 8) wv = b1[col];
    g_w1[idx] = (_Float16)wv;
  } else if (idx < TOTW1 + TOT1) {
    const int id = idx - TOTW1;
    const int i = id & 7, l = (id >> 3) & 63, nk = id >> 9;
    const int kt = nk % KTG, nt = nk / KTG;
    const int g = l >> 4, c = l & 15;
    const int k = kt * 32 + g * 8 + i;        // 0..703
    const int grp = nt / 13;                  // 0=z 1=r 2=xh 3=hh
    const int jj = (nt - grp * 13) * 16 + c;  // 0..207
    float wv = 0.f;
    if (jj < HID) {
      if (grp == 0) {
        if (k < H1) wv = Wg[k * 600 + jj];
        else if (k < H1 + HID) wv = Ug[(k - H1) * 600 + jj];
      } else if (grp == 1) {
        if (k < H1) wv = Wg[k * 600 + 200 + jj];
        else if (k < H1 + HID) wv = Ug[(k - H1) * 600 + 200 + jj];
      } else if (grp == 2) {
        if (k < H1) wv = Wg[k * 600 + 400 + jj];           // xh: a1 rows only
      } else {
        if (k >= H1 && k < H1 + HID) wv = Ug[(k - H1) * 600 + 400 + jj];  // hh
      }
    }
    g_wcat[id] = (_Float16)wv;
  } else if (idx < TOTW1 + TOT1 + TOT2) {
    const int id = idx - TOTW1 - TOT1;
    const int i = id & 7, l = (id >> 3) & 63, nk = id >> 9;
    const int kt = nk % KT2, nt = nk / KT2;
    const int g = l >> 4, c = l & 15;
    const int k = kt * 32 + g * 8 + i;        // 0..223
    const int col = nt * 16 + c;              // 0..319 (all real)
    float wv = 0.f;
    if (k < HID) wv = W2[k * H2 + col];
    else if (k == 200) wv = b2[col];          // ones-row at k_h=200 (k=680)
    g_w2[id] = (_Float16)wv;
  } else if (idx < TOTW1 + TOT1 + TOT2 + TOT3) {
    const int id = idx - TOTW1 - TOT1 - TOT2;
    const int i = id & 7, l = (id >> 3) & 63, kt = id >> 9;
    const int g = l >> 4, c = l & 15;
    const int k = kt * 32 + g * 8 + i;        // 0..319
    g_w3[id] = (_Float16)((c < 8) ? W3[k * 8 + c] : 0.f);
  }
}

// ---------------- main recurrent kernel ----------------
__global__
__attribute__((amdgpu_flat_work_group_size(NTHR, NTHR)))
__attribute__((amdgpu_waves_per_eu(4, 4)))
void knet_kernel(
    const float* __restrict__ y,    // [T,B,2]
    const float* __restrict__ Fm,   // [4,4]
    const float* __restrict__ Hm,   // [2,4]
    const float* __restrict__ bg,   // [2,600]
    const float* __restrict__ b3,   // [8]
    const float* __restrict__ hn0,  // [B,200]
    float* __restrict__ out)        // [T,B,4]
{
  // a1 (k 0..479) single fp16; slots 0..9 reused for a2 (cols 0..319) E->F
  __shared__ alignas(16) _Float16 sA1[KTA * 2 * 512];    // 30720 B
  // h region (k_h 0..223 incl. 1.0@200 pad), exact hi/lo
  __shared__ alignas(16) _Float16 sAhh[KT2 * 2 * 512];   // 14336 B
  __shared__ alignas(16) _Float16 sAhl[KT2 * 2 * 512];   // 14336 B
  __shared__ alignas(16) float s_in8T[8][BR];
  __shared__ alignas(16) float s_kgp[2][BR][8];          // KG k-half partials
  __shared__ alignas(16) float s_bias[4][HID];
  __shared__ alignas(16) float s_fh[32];                 // Fm[16], Hm[8]
  __shared__ alignas(16) float s_b3[8];
  // persistent per-row filter state, double-buffered by t-parity (r8)
  __shared__ alignas(16) float s_prior2[2][BR][4];
  __shared__ alignas(16) float s_d2[2][BR][2];

  const int tid  = threadIdx.x;
  const int lane = tid & 63;
  const int wid  = __builtin_amdgcn_readfirstlane(tid >> 6);  // 0..15
  const int row0 = blockIdx.x * BR;
  const int rl   = lane & 31;
  const int g4   = (lane >> 4) << 2;
  const int ab   = lane * 8;
  const int c16  = lane & 15;

  // ---- init ----
  if (tid < HID) {
    s_bias[0][tid] = bg[tid]       + bg[600 + tid];   // z
    s_bias[1][tid] = bg[200 + tid] + bg[800 + tid];   // r
    s_bias[2][tid] = bg[400 + tid];                   // xh (input bias)
    s_bias[3][tid] = bg[1000 + tid];                  // hh (recurrent bias)
  }
  if (tid < 16) s_fh[tid] = Fm[tid];
  else if (tid < 24) s_fh[tid] = Hm[tid - 16];
  if (tid < 8) s_b3[tid] = b3[tid];
  if (tid < BR * 4) s_prior2[0][tid >> 2][tid & 3] = 0.f;
  if (tid < BR * 2) s_d2[0][tid >> 1][tid & 1] = 0.f;
  for (int e = tid; e < HID * BR; e += NTHR) {          // hn0 -> hi/lo
    const int j = e >> 5, r = e & 31;
    const float h0 = hn0[(size_t)(row0 + r) * HID + j];
    const int off = fragoff(j, r);
    const _Float16 hi = (_Float16)h0;
    sAhh[off] = hi;
    sAhl[off] = (_Float16)(h0 - (float)hi);
  }
  for (int e = tid; e < 24 * BR; e += NTHR) {   // k_h 200..223: 1.0 then 0
    const int kh = 200 + (e >> 5), r = e & 31;
    const int off = fragoff(kh, r);
    sAhh[off] = (_Float16)((kh == 200) ? 1.f : 0.f);
    sAhl[off] = (_Float16)0.f;
  }
  __syncthreads();

  for (int t = 0; t < T_STEPS; ++t) {
    const int p = t & 1;
    // ================= phase 1: F2(t-1) + A(t) + W1-GEMM(t) =================
    {
      float post[4] = {0.f, 0.f, 0.f, 0.f};
      if (t > 0) {
        float kg[8];
#pragma unroll
        for (int cc = 0; cc < 8; ++cc)
          kg[cc] = s_kgp[0][rl][cc] + s_kgp[1][rl][cc] + s_b3[cc];
        const float pd0 = s_d2[p][rl][0], pd1 = s_d2[p][rl][1];
#pragma unroll
        for (int m = 0; m < 4; ++m)
          post[m] = s_prior2[p][rl][m] + kg[2 * m] * pd0 + kg[2 * m + 1] * pd1;
        if (wid == 0 && lane < BR) {
          float4 o; o.x = post[0]; o.y = post[1]; o.z = post[2]; o.w = post[3];
          *(float4*)&out[((size_t)(t - 1) * BATCH + row0 + rl) * 4] = o;
        }
      }
      // ---- A: prior / innovation / features (redundant per wave) ----
      float opri[4], np[4];
#pragma unroll
      for (int m = 0; m < 4; ++m) opri[m] = s_prior2[p][rl][m];
#pragma unroll
      for (int m = 0; m < 4; ++m) {
        float s = 0.f;
#pragma unroll
        for (int j = 0; j < 4; ++j) s += s_fh[m * 4 + j] * post[j];
        np[m] = s;
      }
      float m0 = 0.f, m1 = 0.f;
#pragma unroll
      for (int m = 0; m < 4; ++m) { m0 += s_fh[16 + m] * np[m]; m1 += s_fh[20 + m] * np[m]; }
      const float2 yv = *(const float2*)&y[((size_t)t * BATCH + row0 + rl) * 2];
      const float d0 = yv.x - m0;
      const float d1 = yv.y - m1;
      float dx[4], ssx = 0.f;
#pragma unroll
      for (int m = 0; m < 4; ++m) { dx[m] = post[m] - opri[m]; ssx += dx[m] * dx[m]; }
      const float idx_ = rsqrtf(fmaxf(ssx, 1e-12f));
      const float idy_ = rsqrtf(fmaxf(d0 * d0 + d1 * d1, 1e-12f));
      if (lane < BR) {   // identical values from all waves: benign
#pragma unroll
        for (int m = 0; m < 4; ++m) s_prior2[p ^ 1][rl][m] = np[m];
        s_d2[p ^ 1][rl][0] = d0;
        s_d2[p ^ 1][rl][1] = d1;
        const float n0 = d0 * idy_, n1 = d1 * idy_;
        s_in8T[0][rl] = n0; s_in8T[1][rl] = n1;
        s_in8T[2][rl] = n0; s_in8T[3][rl] = n1;
#pragma unroll
        for (int m = 0; m < 4; ++m) s_in8T[4 + m][rl] = dx[m] * idx_;
      }
    }
    {   // ---- W1-GEMM: a1 = relu([in8,1] @ [W1;b1]), 2 tiles/wave ----
      f16x8 ah0 = f16x8_zero(), al0 = f16x8_zero();
      f16x8 ah1 = f16x8_zero(), al1 = f16x8_zero();
      const int g = lane >> 4;
      if (g == 0) {
#pragma unroll
        for (int i = 0; i < 8; ++i) {
          const float v0 = s_in8T[i][c16];
          const float v1 = s_in8T[i][c16 + 16];
          const _Float16 h0 = (_Float16)v0; ah0[i] = h0; al0[i] = (_Float16)(v0 - (float)h0);
          const _Float16 h1 = (_Float16)v1; ah1[i] = h1; al1[i] = (_Float16)(v1 - (float)h1);
        }
      } else if (g == 1) {
        ah0[0] = (_Float16)1.f;   // ones-row k=8 -> b1
        ah1[0] = (_Float16)1.f;
      }
      f32x4 p00 = {0.f, 0.f, 0.f, 0.f}, p01 = p00, p10 = p00, p11 = p00;
      const f16x8 w1a = *(const f16x8*)&g_w1[(size_t)wid * 512 + ab];
      p00 = MFMA16(ah0, w1a, p00); p00 = MFMA16(al0, w1a, p00);
      p01 = MFMA16(ah1, w1a, p01); p01 = MFMA16(al1, w1a, p01);
      const bool hasB = (wid < 14);
      if (hasB) {
        const f16x8 w1b = *(const f16x8*)&g_w1[(size_t)(16 + wid) * 512 + ab];
        p10 = MFMA16(ah0, w1b, p10); p10 = MFMA16(al0, w1b, p10);
        p11 = MFMA16(ah1, w1b, p11); p11 = MFMA16(al1, w1b, p11);
      }
      // single-fp16 a1 store (r11-validated numerics)
#define ASTORE1(A0, A1, COLBASE)                                     \
      { const int col = (COLBASE) + c16;                             \
        _Pragma("unroll")                                            \
        for (int reg = 0; reg < 4; ++reg) {                          \
          sA1[fragoff(col, g4 + reg)]      = (_Float16)fmaxf(A0[reg], 0.f); \
          sA1[fragoff(col, 16 + g4 + reg)] = (_Float16)fmaxf(A1[reg], 0.f); \
        } }
      ASTORE1(p00, p01, wid * 16)
      if (hasB) ASTORE1(p10, p11, (16 + wid) * 16)
    }
    __syncthreads();

    // == phase C: gates GEMM (waves 0..12; a1 single-A, h hi/lo; B depth-1) ==
    f32x4 aZ0 = {0.f, 0.f, 0.f, 0.f}, aZ1 = aZ0, aR0 = aZ0, aR1 = aZ0;
    f32x4 aX0 = aZ0, aX1 = aZ0, aH0 = aZ0, aH1 = aZ0;
    if (wid < 13) {
      const _Float16* bzp = g_wcat + ((size_t)(0  + wid) * KTG) * 512 + ab;
      const _Float16* brp = g_wcat + ((size_t)(13 + wid) * KTG) * 512 + ab;
      const _Float16* bxp = g_wcat + ((size_t)(26 + wid) * KTG) * 512 + ab;
      const _Float16* bhp = g_wcat + ((size_t)(39 + wid) * KTG) * 512 + ab;
#define LD3(KT) (((KT) < KTA) ? *(const f16x8*)(bxp + (KT) * 512) \
                              : *(const f16x8*)(bhp + (KT) * 512))
      f16x8 bzC = *(const f16x8*)(bzp);
      f16x8 brC = *(const f16x8*)(brp);
      f16x8 bxC = LD3(0);
#pragma unroll
      for (int kt = 0; kt < KTG; ++kt) {
        // B(kt+1) global loads, issued before kt's MFMA cluster
        f16x8 bzN, brN, bxN;
        if (kt + 1 < KTG) {
          bzN = *(const f16x8*)(bzp + (kt + 1) * 512);
          brN = *(const f16x8*)(brp + (kt + 1) * 512);
          bxN = LD3(kt + 1);
        }
        if (kt < KTA) {
          // a1 region: single fp16 A
          const int _o = kt * 1024 + ab;
          const f16x8 ca0 = *(const f16x8*)&sA1[_o];
          const f16x8 ca1 = *(const f16x8*)&sA1[_o + 512];
          SBAR();
          aZ0 = MFMA16(ca0, bzC, aZ0);
          aZ1 = MFMA16(ca1, bzC, aZ1);
          aR0 = MFMA16(ca0, brC, aR0);
          aR1 = MFMA16(ca1, brC, aR1);
          aX0 = MFMA16(ca0, bxC, aX0);
          aX1 = MFMA16(ca1, bxC, aX1);
        } else {
          // h region: hi/lo A
          const int _o = (kt - KTA) * 1024 + ab;
          const f16x8 cah0 = *(const f16x8*)&sAhh[_o];
          const f16x8 cal0 = *(const f16x8*)&sAhl[_o];
          const f16x8 cah1 = *(const f16x8*)&sAhh[_o + 512];
          const f16x8 cal1 = *(const f16x8*)&sAhl[_o + 512];
          SBAR();
          aZ0 = MFMA16(cah0, bzC, aZ0);  aZ0 = MFMA16(cal0, bzC, aZ0);
          aZ1 = MFMA16(cah1, bzC, aZ1);  aZ1 = MFMA16(cal1, bzC, aZ1);
          aR0 = MFMA16(cah0, brC, aR0);  aR0 = MFMA16(cal0, brC, aR0);
          aR1 = MFMA16(cah1, brC, aR1);  aR1 = MFMA16(cal1, brC, aR1);
          aH0 = MFMA16(cah0, bxC, aH0);  aH0 = MFMA16(cal0, bxC, aH0);
          aH1 = MFMA16(cah1, bxC, aH1);  aH1 = MFMA16(cal1, bxC, aH1);
        }
        if (kt + 1 < KTG) { bzC = bzN; brC = brN; bxC = bxN; }
      }
#undef LD3
    }
    __syncthreads();   // all h reads done before in-place h update

    // ================= phase D: in-register GRU update =================
    if (wid < 13) {
      const int j = wid * 16 + c16;
      if (j < HID) {
        const float bz  = s_bias[0][j], brb = s_bias[1][j];
        const float bxh = s_bias[2][j], bhh = s_bias[3][j];
#define GRU1(AZ, AR, AX, AH, MB)                                         \
        _Pragma("unroll")                                                \
        for (int reg = 0; reg < 4; ++reg) {                              \
          const int r = (MB) * 16 + g4 + reg;                            \
          const int off = fragoff(j, r);                                 \
          const float hold = (float)sAhh[off] + (float)sAhl[off];        \
          const float z  = sigmoid_(AZ[reg] + bz);                       \
          const float rr = sigmoid_(AR[reg] + brb);                      \
          const float hc = tanh_((AX[reg] + bxh) + rr * (AH[reg] + bhh));\
          const float hn = z * hold + (1.f - z) * hc;                    \
          const _Float16 qh = (_Float16)hn;                              \
          sAhh[off] = qh;                                                \
          sAhl[off] = (_Float16)(hn - (float)qh);                       \
        }
        GRU1(aZ0, aR0, aX0, aH0, 0)
        GRU1(aZ1, aR1, aX1, aH1, 1)
#undef GRU1
      }
    }
    __syncthreads();

    // == phase E: a2 = relu(h @ W2 + b2); h hi/lo A, B depth-1, pinned ==
    {
      f32x4 e00 = {0.f, 0.f, 0.f, 0.f}, e01 = e00, e10 = e00, e11 = e00;
      const _Float16* w2a = g_w2 + ((size_t)wid * KT2) * 512 + ab;
      const _Float16* w2b = g_w2 + ((size_t)(16 + wid) * KT2) * 512 + ab;
      f16x8 baC = *(const f16x8*)(w2a);
      f16x8 bbC = (wid < 4) ? *(const f16x8*)(w2b) : f16x8_zero();
#pragma unroll
      for (int qt = 0; qt < KT2; ++qt) {
        const int _o = qt * 1024 + ab;
        const f16x8 cah0 = *(const f16x8*)&sAhh[_o];
        const f16x8 cal0 = *(const f16x8*)&sAhl[_o];
        const f16x8 cah1 = *(const f16x8*)&sAhh[_o + 512];
        const f16x8 cal1 = *(const f16x8*)&sAhl[_o + 512];
        f16x8 baN, bbN;
        if (qt + 1 < KT2) {
          baN = *(const f16x8*)(w2a + (qt + 1) * 512);
          if (wid < 4) bbN = *(const f16x8*)(w2b + (qt + 1) * 512);
        }
        SBAR();
        e00 = MFMA16(cah0, baC, e00); e00 = MFMA16(cal0, baC, e00);
        e01 = MFMA16(cah1, baC, e01); e01 = MFMA16(cal1, baC, e01);
        if (wid < 4) {
          e10 = MFMA16(cah0, bbC, e10); e10 = MFMA16(cal0, bbC, e10);
          e11 = MFMA16(cah1, bbC, e11); e11 = MFMA16(cal1, bbC, e11);
        }
        if (qt + 1 < KT2) { baC = baN; if (wid < 4) bbC = bbN; }
      }
      // a2 -> sA1 slots 0..9, single fp16 (b2 folded via ones-row)
      ASTORE1(e00, e01, wid * 16)                       // cols < 256
      if (wid < 4) ASTORE1(e10, e11, (16 + wid) * 16)   // cols 256..319
#undef ASTORE1
    }
    __syncthreads();

    // ========== phase F: KG partials (waves 0..3 = m-half x k-half) ==========
    if (wid < 4) {
      const int mB = wid & 1, half = wid >> 1;
      f32x4 ka = {0.f, 0.f, 0.f, 0.f};
      const _Float16* w3p = g_w3 + ab;
#pragma unroll
      for (int q = 0; q < 5; ++q) {
        const int kt3 = half * 5 + q;
        const int _o = kt3 * 1024 + mB * 512 + ab;
        const f16x8 a  = *(const f16x8*)&sA1[_o];
        const f16x8 bw = *(const f16x8*)(w3p + kt3 * 512);
        ka = MFMA16(a, bw, ka);
      }
      if (c16 < 8) {
        const int rb = mB * 16 + g4;
#pragma unroll
        for (int reg = 0; reg < 4; ++reg) s_kgp[half][rb + reg][c16] = ka[reg];
      }
    }
    __syncthreads();
  }

  // ---- final F2 (t = T_STEPS, parity 0) ----
  {
    float kg[8];
#pragma unroll
    for (int cc = 0; cc < 8; ++cc)
      kg[cc] = s_kgp[0][rl][cc] + s_kgp[1][rl][cc] + s_b3[cc];
    const float pd0 = s_d2[0][rl][0], pd1 = s_d2[0][rl][1];
    if (wid == 0 && lane < BR) {
      float4 o;
      o.x = s_prior2[0][rl][0] + kg[0] * pd0 + kg[1] * pd1;
      o.y = s_prior2[0][rl][1] + kg[2] * pd0 + kg[3] * pd1;
      o.z = s_prior2[0][rl][2] + kg[4] * pd0 + kg[5] * pd1;
      o.w = s_prior2[0][rl][3] + kg[6] * pd0 + kg[7] * pd1;
      *(float4*)&out[((size_t)(T_STEPS - 1) * BATCH + row0 + rl) * 4] = o;
    }
  }
}

}  // namespace

extern "C" void kernel_launch(void* const* d_in, const int* in_sizes, int n_in,
                              void* d_out, int out_size, void* d_ws, size_t ws_size,
                              hipStream_t stream) {
  const float* y   = (const float*)d_in[0];
  const float* Fm  = (const float*)d_in[1];
  const float* Hm  = (const float*)d_in[2];
  const float* W1  = (const float*)d_in[3];
  const float* b1  = (const float*)d_in[4];
  const float* Wg  = (const float*)d_in[5];
  const float* Ug  = (const float*)d_in[6];
  const float* bg  = (const float*)d_in[7];
  const float* W2  = (const float*)d_in[8];
  const float* b2  = (const float*)d_in[9];
  const float* W3  = (const float*)d_in[10];
  const float* b3  = (const float*)d_in[11];
  const float* hn0 = (const float*)d_in[12];
  float* out = (float*)d_out;

  constexpr int PREP_TOT = (NTW1 + NTG * KTG + NT2 * KT2 + KT3) * 512;
  prep_kernel<<<(PREP_TOT + 255) / 256, 256, 0, stream>>>(W1, b1, Wg, Ug, W2, b2, W3);
  knet_kernel<<<BATCH / BR, NTHR, 0, stream>>>(y, Fm, Hm, bg, b3, hn0, out);
}